// Round 6
// baseline (231.550 us; speedup 1.0000x reference)
//
#include <hip/hip_runtime.h>
#include <hip/hip_fp16.h>
#include <stdint.h>

#define N_EDGES 200000
#define N_NODES 50000
#define BM 256
#define NT 512
#define GTOT 36   // 36 groups x 2 tiles = 72 K-tiles

typedef _Float16 f16x8 __attribute__((ext_vector_type(8)));
typedef float f32x4 __attribute__((ext_vector_type(4)));

// ---- prep_w: W -> f16, scales folded. wt[T*2048 + w*32 + kk] = f16(scale*W[k=T*32+kk][w])
__global__ void prep_w(const float* __restrict__ W0, const float* __restrict__ W1,
                       const float* __restrict__ W2, uint16_t* __restrict__ wt) {
  int o = blockIdx.x * 256 + threadIdx.x;     // 147456 total
  int T = o >> 11, r = o & 2047, w = r >> 5, kk = r & 31;
  int k = T * 32 + kk;
  const float AS = 1.0f / 48.0f;                  // 1/sqrt(2304)
  const float AV = AS * 0.57735026918962576f;     // /sqrt(3)
  const float AT = AS * 0.44721359549995794f;     // /sqrt(5)
  float val;
  if (k < 1024)      val = AS * W0[(k >> 5) * 2048 + (k & 31) * 64 + w];
  else if (k < 2048) { int k2 = k - 1024; val = AV * W1[(k2 >> 5) * 2048 + (k2 & 31) * 64 + w]; }
  else               { int k2 = k - 2048; val = AT * W2[(k2 >> 4) * 1024 + (k2 & 15) * 64 + w]; }
  __half h = __float2half(val);
  wt[o] = *reinterpret_cast<uint16_t*>(&h);
}

// ---- prep_tables: node_tensors -> TA (u-major, 296 u16/row) + TB (m-major, 216 u16/row)
__global__ void prep_tables(const float* __restrict__ nt,
                            uint16_t* __restrict__ ta, uint16_t* __restrict__ tb) {
  long long o = (long long)blockIdx.x * 256 + threadIdx.x;
  if (o >= (long long)N_NODES * 296) return;
  int node = (int)(o / 296);
  int r = (int)(o - (long long)node * 296);
  const float* x = nt + (size_t)node * 208;
  float va = 0.f;
  if (r < 32) va = x[r];
  else if (r < 160) { int q = r - 32;  int u = q >> 2, m = q & 3;  if (m < 3) va = x[32 + u * 3 + m]; }
  else if (r < 288) { int q = r - 160; int u = q >> 3, m = q & 7;  if (m < 5) va = x[128 + u * 5 + m]; }
  __half ha = __float2half(va);
  ta[(size_t)node * 296 + r] = *reinterpret_cast<uint16_t*>(&ha);
  if (r < 216) {
    float vb = 0.f;
    if (r < 32) vb = x[r];
    else if (r < 128) { int q = r - 32;  int m = q >> 5, v = q & 31; vb = x[32 + v * 3 + m]; }
    else if (r < 208) { int q = r - 128; int m = q >> 4, v = q & 15; vb = x[128 + v * 5 + m]; }
    __half hb = __float2half(vb);
    tb[(size_t)node * 216 + r] = *reinterpret_cast<uint16_t*>(&hb);
  }
}

__device__ __forceinline__ void gload16(const void* g, void* l) {
  __builtin_amdgcn_global_load_lds(
      (const __attribute__((address_space(1))) void*)g,
      (__attribute__((address_space(3))) void*)l, 16, 0, 0);
}

// broadcast one half (sel=0 low, sel=1 high) of a u32 to both halves of a __half2
__device__ __forceinline__ __half2 bcast_half(uint32_t w, int sel) {
  uint32_t hv = sel ? (w >> 16) : (w & 0xffffu);
  hv |= hv << 16;
  union { uint32_t u; __half2 h; } cv; cv.u = hv;
  return cv.h;
}

// ---- W pipeline: 4-slot x 8192B LDS ring, 2 tiles (4096B each) per group.
// STAGEW(G): all 512 threads issue ONE global_load_lds each -> 8192B group.
// Counted vmcnt (never 0 in steady state) + raw s_barrier: pipeline never drains.
#define STAGEW(G)                                                               \
  if ((G) < GTOT) {                                                             \
    gload16((const char*)wt + (size_t)(G) * 8192 + tid * 16,                    \
            (void*)(smem + ((G) & 3) * 8192 + (tid >> 6) * 1024));              \
  }
// correctness: stage(G) is drained iff >=N newer VMEM ops exist; stages G+1,G+2
// are always newer in steady state (N=2); tail shrinks to 1 then 0.
#define WAITV(G)                                                                \
  do {                                                                          \
    if ((G) >= GTOT - 1)      asm volatile("s_waitcnt vmcnt(0)" ::: "memory");  \
    else if ((G) == GTOT - 2) asm volatile("s_waitcnt vmcnt(1)" ::: "memory");  \
    else                      asm volatile("s_waitcnt vmcnt(2)" ::: "memory");  \
  } while (0)
#define BARRIER() asm volatile("s_barrier" ::: "memory")

#define LDSW(WRA, G, TL)                                                        \
  { const uint4* wb_ = (const uint4*)(smem + ((G) & 3) * 8192 + (TL) * 4096);   \
    _Pragma("unroll") for (int nf = 0; nf < 4; ++nf)                            \
      WRA[nf] = wb_[nf * 64 + lo4]; }

#define MSTEPA(WRA, A)                                                          \
  _Pragma("unroll") for (int mf = 0; mf < 2; ++mf)                              \
  _Pragma("unroll") for (int nf = 0; nf < 4; ++nf)                              \
    acc[mf][nf] = __builtin_amdgcn_mfma_f32_16x16x32_f16(                       \
        (A)[mf], *(const f16x8*)&WRA[nf], acc[mf][nf], 0, 0, 0);

// S build from registers: element T_ of this lane's row-slice sS (u16[32]).
#define BUILD_SR(T_, A)                                                         \
  _Pragma("unroll") for (int mf = 0; mf < 2; ++mf) {                            \
    __half2 s1b2 = bcast_half(sS[mf][(T_) >> 1], (T_) & 1);                     \
    union { uint32_t u[4]; f16x8 v; } au_;                                      \
    _Pragma("unroll") for (int q = 0; q < 4; ++q) {                             \
      __half2 p = __hmul2(s1b2, ((const __half2*)&s2pk[mf])[q]);                \
      au_.u[q] = *(uint32_t*)&p;                                                \
    }                                                                           \
    (A)[mf] = au_.v;                                                            \
  }

// V build from registers: UL in 0..7 within current 8-u group (vS = 64B slice).
#define BUILD_VR(UL, A)                                                         \
  _Pragma("unroll") for (int mf = 0; mf < 2; ++mf) {                            \
    __half2 va0 = bcast_half(vS[mf][(UL) * 2], 0);                              \
    __half2 va1 = bcast_half(vS[mf][(UL) * 2], 1);                              \
    __half2 va2 = bcast_half(vS[mf][(UL) * 2 + 1], 0);                          \
    union { uint32_t u[4]; f16x8 v; } au_;                                      \
    _Pragma("unroll") for (int q = 0; q < 4; ++q) {                             \
      __half2 p = __hmul2(va0, ((const __half2*)&v2pk[mf][0])[q]);              \
      p = __hfma2(va1, ((const __half2*)&v2pk[mf][1])[q], p);                   \
      p = __hfma2(va2, ((const __half2*)&v2pk[mf][2])[q], p);                   \
      au_.u[q] = *(uint32_t*)&p;                                                \
    }                                                                           \
    (A)[mf] = au_.v;                                                            \
  }

// T build from registers: TT_ in 0..3 within current half (tS already gh-selected).
#define BUILD_TR(TT_, A)                                                        \
  _Pragma("unroll") for (int mm = 0; mm < 2; ++mm) {                            \
    __half2 tb0 = bcast_half(tS[mm][(TT_) * 4 + 0], 0);                         \
    __half2 tb1 = bcast_half(tS[mm][(TT_) * 4 + 0], 1);                         \
    __half2 tb2 = bcast_half(tS[mm][(TT_) * 4 + 1], 0);                         \
    __half2 tb3 = bcast_half(tS[mm][(TT_) * 4 + 1], 1);                         \
    __half2 tb4 = bcast_half(tS[mm][(TT_) * 4 + 2], 0);                         \
    union { uint32_t u[4]; f16x8 v; } au_;                                      \
    _Pragma("unroll") for (int q = 0; q < 4; ++q) {                             \
      __half2 p = __hmul2(tb0, ((const __half2*)&t2pk[mm][0])[q]);              \
      p = __hfma2(tb1, ((const __half2*)&t2pk[mm][1])[q], p);                   \
      p = __hfma2(tb2, ((const __half2*)&t2pk[mm][2])[q], p);                   \
      p = __hfma2(tb3, ((const __half2*)&t2pk[mm][3])[q], p);                   \
      p = __hfma2(tb4, ((const __half2*)&t2pk[mm][4])[q], p);                   \
      au_.u[q] = *(uint32_t*)&p;                                                \
    }                                                                           \
    (A)[mm] = au_.v;                                                            \
  }

// LDS union: W ring [4][8192] = 32768 B during K-loop; f32 etile [256][68]
// = 69632 B in the epilogue (overlaid). Block LDS = 69632 B; 2x = 139264 <= 160K.
// x1/TB stay register-staged from global (no x1 LDS, no ds_read on A side).
// __launch_bounds__(512,2): only proven non-spilling multi-wave setting
// (R0->128 VGPR, R2->84; (512,4)/(1024,1) forced 64 -> 180MB spills).
__global__ __launch_bounds__(NT, 2) void edge_main(
    const uint16_t* __restrict__ ta, const uint16_t* __restrict__ tbl,
    const int* __restrict__ ei, const uint16_t* __restrict__ wt,
    const float* __restrict__ A1, const float* __restrict__ b1,
    const float* __restrict__ A2, const float* __restrict__ b2,
    float* __restrict__ out)
{
  __shared__ alignas(16) unsigned char smem[69632];
  const int tid = threadIdx.x;
  const int e0 = blockIdx.x * BM;
  const int lane = tid & 63, c = lane & 15, g = lane >> 4;
  const int wv = tid >> 6;           // wave id 0..7, owns 32 edges
  const int lo4 = c * 4 + g;

  const unsigned char* x1p[2];
  const unsigned char* tbp[2];
  #pragma unroll
  for (int mf = 0; mf < 2; ++mf) {
    int e = e0 + wv * 32 + mf * 16 + c;
    if (e > N_EDGES - 1) e = N_EDGES - 1;
    int src = ei[e];
    int dst = ei[N_EDGES + e];
    x1p[mf] = (const unsigned char*)ta + (size_t)src * 592;
    tbp[mf] = (const unsigned char*)tbl + (size_t)dst * 432;
  }

  f32x4 acc[2][4];
  #pragma unroll
  for (int mf = 0; mf < 2; ++mf)
    #pragma unroll
    for (int nf = 0; nf < 4; ++nf) acc[mf][nf] = (f32x4){0.f, 0.f, 0.f, 0.f};

  // prologue: stage groups 0,1
  STAGEW(0);
  STAGEW(1);

  // ---- S phase: groups 0..15 (tiles 0..31) ----
  {
    uint4 s2pk[2];
    #pragma unroll
    for (int mf = 0; mf < 2; ++mf) s2pk[mf] = *(const uint4*)(tbp[mf] + g * 16);
    uint32_t sS[2][16];
    #pragma unroll
    for (int mf = 0; mf < 2; ++mf)
      #pragma unroll
      for (int i = 0; i < 4; ++i) {
        uint4 q_ = *(const uint4*)(x1p[mf] + i * 16);
        sS[mf][i * 4 + 0] = q_.x; sS[mf][i * 4 + 1] = q_.y;
        sS[mf][i * 4 + 2] = q_.z; sS[mf][i * 4 + 3] = q_.w;
      }
    #pragma unroll
    for (int q = 0; q < 16; ++q) {
      STAGEW(q + 2);
      WAITV(q);
      BARRIER();
      uint4 wrA[4], wrB[4];
      LDSW(wrA, q, 0); LDSW(wrB, q, 1);
      { f16x8 a[2]; BUILD_SR(2 * q, a);     MSTEPA(wrA, a); }
      { f16x8 a[2]; BUILD_SR(2 * q + 1, a); MSTEPA(wrB, a); }
    }
  }

  // ---- V phase: groups 16..31 (tiles 32..63) ----
  {
    uint4 v2pk[2][3];
    #pragma unroll
    for (int mf = 0; mf < 2; ++mf)
      #pragma unroll
      for (int m3 = 0; m3 < 3; ++m3)
        v2pk[mf][m3] = *(const uint4*)(tbp[mf] + 64 + m3 * 64 + g * 16);
    uint32_t vS[2][16];
    #pragma unroll
    for (int q = 0; q < 16; ++q) {
      if ((q & 3) == 0) {
        const int G4 = q >> 2;
        #pragma unroll
        for (int mf = 0; mf < 2; ++mf)
          #pragma unroll
          for (int i = 0; i < 4; ++i) {
            uint4 q_ = *(const uint4*)(x1p[mf] + 64 + G4 * 64 + i * 16);
            vS[mf][i * 4 + 0] = q_.x; vS[mf][i * 4 + 1] = q_.y;
            vS[mf][i * 4 + 2] = q_.z; vS[mf][i * 4 + 3] = q_.w;
          }
      }
      STAGEW(16 + q + 2);
      WAITV(16 + q);
      BARRIER();
      uint4 wrA[4], wrB[4];
      LDSW(wrA, 16 + q, 0); LDSW(wrB, 16 + q, 1);
      { f16x8 a[2]; BUILD_VR((2 * q) & 7, a);     MSTEPA(wrA, a); }
      { f16x8 a[2]; BUILD_VR((2 * q + 1) & 7, a); MSTEPA(wrB, a); }
    }
  }

  // ---- T phase: groups 32..35 (tiles 64..71) ----
  {
    uint4 t2pk[2][5];
    #pragma unroll
    for (int mm = 0; mm < 2; ++mm)
      #pragma unroll
      for (int m5 = 0; m5 < 5; ++m5)
        t2pk[mm][m5] = *(const uint4*)(tbp[mm] + 256 + m5 * 32 + (g & 1) * 16);
    const int gh16 = (g >> 1) * 16;
    uint32_t tS[2][16];
    #pragma unroll
    for (int q = 0; q < 4; ++q) {
      if ((q & 1) == 0) {
        const int H = q >> 1;
        #pragma unroll
        for (int mm = 0; mm < 2; ++mm)
          #pragma unroll
          for (int i = 0; i < 4; ++i) {
            uint4 q_ = *(const uint4*)(x1p[mm] + 320 + gh16 + H * 128 + i * 32);
            tS[mm][i * 4 + 0] = q_.x; tS[mm][i * 4 + 1] = q_.y;
            tS[mm][i * 4 + 2] = q_.z; tS[mm][i * 4 + 3] = q_.w;
          }
      }
      STAGEW(32 + q + 2);
      WAITV(32 + q);
      BARRIER();
      uint4 wrA[4], wrB[4];
      LDSW(wrA, 32 + q, 0); LDSW(wrB, 32 + q, 1);
      { f16x8 a[2]; BUILD_TR((2 * q) & 3, a);     MSTEPA(wrA, a); }
      { f16x8 a[2]; BUILD_TR((2 * q + 1) & 3, a); MSTEPA(wrB, a); }
    }
  }

  // ---- epilogue: all waves done with W ring -> overlay f32 etile ----
  BARRIER();
  float* etile = (float*)smem;
  #pragma unroll
  for (int mf = 0; mf < 2; ++mf)
    #pragma unroll
    for (int nf = 0; nf < 4; ++nf)
      #pragma unroll
      for (int rr = 0; rr < 4; ++rr)
        etile[(size_t)(wv * 32 + mf * 16 + g * 4 + rr) * 68 + nf * 16 + c] =
            acc[mf][nf][rr];
  __syncthreads();

  // ---- MLP head: 2 threads/edge (j-halves of 16), 512 threads = 256 edges ----
  {
    int el = tid >> 1, jh = tid & 1;
    const float* er = etile + (size_t)el * 68;
    float hacc[16];
    #pragma unroll
    for (int j = 0; j < 16; ++j) hacc[j] = b1[jh * 16 + j];
    for (int w4 = 0; w4 < 16; ++w4) {
      float4 ea = *(const float4*)(er + w4 * 4);
      #pragma unroll
      for (int q2 = 0; q2 < 4; ++q2) {
        float ev = (&ea.x)[q2];
        int w = w4 * 4 + q2;
        float4 a0 = *(const float4*)(A1 + w * 32 + jh * 16);
        float4 a1 = *(const float4*)(A1 + w * 32 + jh * 16 + 4);
        float4 a2 = *(const float4*)(A1 + w * 32 + jh * 16 + 8);
        float4 a3 = *(const float4*)(A1 + w * 32 + jh * 16 + 12);
        hacc[0]  += ev * a0.x; hacc[1]  += ev * a0.y; hacc[2]  += ev * a0.z; hacc[3]  += ev * a0.w;
        hacc[4]  += ev * a1.x; hacc[5]  += ev * a1.y; hacc[6]  += ev * a1.z; hacc[7]  += ev * a1.w;
        hacc[8]  += ev * a2.x; hacc[9]  += ev * a2.y; hacc[10] += ev * a2.z; hacc[11] += ev * a2.w;
        hacc[12] += ev * a3.x; hacc[13] += ev * a3.y; hacc[14] += ev * a3.z; hacc[15] += ev * a3.w;
      }
    }
    float o = 0.f;
    #pragma unroll
    for (int j = 0; j < 16; ++j) {
      float z = hacc[j];
      o += (z / (1.f + __expf(-z))) * A2[jh * 16 + j];
    }
    o += __shfl_xor(o, 1);
    int e = e0 + el;
    if (jh == 0 && e < N_EDGES) out[e] = o + b2[0];
  }
}

extern "C" void kernel_launch(void* const* d_in, const int* in_sizes, int n_in,
                              void* d_out, int out_size, void* d_ws, size_t ws_size,
                              hipStream_t stream) {
  const float* nt = (const float*)d_in[0];
  const int*   ei = (const int*)d_in[1];
  const float* W0 = (const float*)d_in[2];
  const float* W1 = (const float*)d_in[3];
  const float* W2 = (const float*)d_in[4];
  const float* A1 = (const float*)d_in[5];
  const float* b1 = (const float*)d_in[6];
  const float* A2 = (const float*)d_in[7];
  const float* b2 = (const float*)d_in[8];
  float* out = (float*)d_out;

  // ws layout: wt 294912B | TA 50000*592 | TB 50000*432   (~51.5 MB total)
  uint16_t* wt = (uint16_t*)d_ws;
  uint16_t* ta = (uint16_t*)((char*)d_ws + 294912);
  uint16_t* tb = (uint16_t*)((char*)d_ws + 294912 + (size_t)N_NODES * 592);

  prep_w<<<576, 256, 0, stream>>>(W0, W1, W2, wt);
  {
    long long tot = (long long)N_NODES * 296;
    int blocks = (int)((tot + 255) / 256);
    prep_tables<<<blocks, 256, 0, stream>>>(nt, ta, tb);
  }
  edge_main<<<(N_EDGES + BM - 1) / BM, NT, 0, stream>>>(ta, tb, ei, wt, A1, b1, A2, b2, out);
}